// Round 3
// baseline (316.650 us; speedup 1.0000x reference)
//
#include <hip/hip_runtime.h>
#include <hip/hip_bf16.h>
#include <math.h>

#define NN 10000
#define EE 160000
#define DIM 256
#define KK 512            // concatenated K = 2*DIM
#define EPS_BN 1e-5f

typedef __attribute__((ext_vector_type(8)))  short bf16x8;
typedef __attribute__((ext_vector_type(16))) float f32x16;

static __device__ __forceinline__ unsigned short f2bf(float f) {
    unsigned u = __float_as_uint(f);
    unsigned r = (u + 0x7fffu + ((u >> 16) & 1u)) >> 16;   // RTNE
    return (unsigned short)r;
}
static __device__ __forceinline__ float bflo(unsigned v) { return __uint_as_float(v << 16); }
static __device__ __forceinline__ float bfhi(unsigned v) { return __uint_as_float(v & 0xffff0000u); }
static __device__ __forceinline__ unsigned packbf(float a, float b) {
    return (unsigned)f2bf(a) | ((unsigned)f2bf(b) << 16);
}

// ---------------- fused prep: cvt_x + cvt_w(3 layers) + zero(deg,stats) ----------------
// grid = 2500 + 1536 + 48 = 4084 blocks of 256
__global__ __launch_bounds__(256) void k_prep(const float* __restrict__ x,
                                              unsigned short* __restrict__ hcat,
                                              const float* __restrict__ Ws0, const float* __restrict__ Wn0,
                                              const float* __restrict__ Ws1, const float* __restrict__ Wn1,
                                              const float* __restrict__ Ws2, const float* __restrict__ Wn2,
                                              unsigned short* __restrict__ wcat,
                                              int* __restrict__ deg_cnt,
                                              float* __restrict__ stats) {
    int b = blockIdx.x;
    int t = threadIdx.x;
    if (b < 2500) {
        int g = b * 256 + t;                  // 640000: row = g>>6, 4 cols
        int r = g >> 6;
        int c4 = (g & 63) * 4;
        float4 v = *(const float4*)(x + (size_t)r * DIM + c4);
        uint2 p;
        p.x = packbf(v.x, v.y);
        p.y = packbf(v.z, v.w);
        *(uint2*)(hcat + (size_t)r * KK + c4) = p;
    } else if (b < 2500 + 1536) {
        int g = (b - 2500) * 256 + t;         // 3 * 131072
        int L = g >> 17;
        int i = g & 131071;
        int k = i >> 8, n = i & 255;
        const float* Ws = (L == 0) ? Ws0 : ((L == 1) ? Ws1 : Ws2);
        const float* Wn = (L == 0) ? Wn0 : ((L == 1) ? Wn1 : Wn2);
        float v = (k < DIM) ? Ws[(size_t)k * DIM + n] : Wn[(size_t)(k - DIM) * DIM + n];
        wcat[(size_t)L * DIM * KK + (size_t)n * KK + k] = f2bf(v);
    } else {
        int g = (b - (2500 + 1536)) * 256 + t;  // 12288 slots
        if (g < NN) deg_cnt[g] = 0;
        int s = g - NN;
        if (s >= 0 && s < 6 * DIM) stats[s] = 0.f;
    }
}

// ---------------- degree histogram ----------------
__global__ void k_deg(const int* __restrict__ dst, int* __restrict__ deg_cnt, int E_) {
    int e = blockIdx.x * 256 + threadIdx.x;
    if (e < E_) atomicAdd(&deg_cnt[dst[e]], 1);
}

// ---------------- exclusive scan over deg (1 block) ----------------
__global__ __launch_bounds__(256) void k_scan(const int* __restrict__ deg_cnt,
                                              int* __restrict__ row_ofs,
                                              int* __restrict__ cursor,
                                              float* __restrict__ inv_deg) {
    __shared__ int part[256];
    int t = threadIdx.x;
    const int CH = (NN + 255) / 256; // 40
    int base = t * CH;
    int s = 0;
    for (int i = 0; i < CH; ++i) {
        int idx = base + i;
        if (idx < NN) s += deg_cnt[idx];
    }
    part[t] = s;
    __syncthreads();
    if (t == 0) {
        int run = 0;
        for (int i = 0; i < 256; ++i) { int v = part[i]; part[i] = run; run += v; }
        row_ofs[NN] = run;
    }
    __syncthreads();
    int off = part[t];
    for (int i = 0; i < CH; ++i) {
        int idx = base + i;
        if (idx < NN) {
            row_ofs[idx] = off;
            cursor[idx]  = off;
            int d = deg_cnt[idx];
            inv_deg[idx] = 1.0f / (float)(d > 1 ? d : 1);
            off += d;
        }
    }
}

// ---------------- CSR fill ----------------
__global__ void k_fill(const int* __restrict__ src, const int* __restrict__ dst,
                       int* __restrict__ cursor, int* __restrict__ csr_src, int E_) {
    int e = blockIdx.x * 256 + threadIdx.x;
    if (e < E_) {
        int p = atomicAdd(&cursor[dst[e]], 1);
        csr_src[p] = src[e];
    }
}

// ---------------- mean aggregation: XCD-sliced L2-resident gather ----------------
// grid = 10000 blocks; blockIdx&7 -> XCD; slice = (blockIdx&7)>>1 (128B feature slice)
// per-XCD gather working set = 10000 * 128B = 1.28 MB -> fits 4 MiB L2.
// wave = one node; 4 groups of 16 lanes, each group one edge (uint2/lane = 128B row slice).
__global__ __launch_bounds__(256) void k_agg(unsigned short* __restrict__ hcat,
                                             const int* __restrict__ row_ofs,
                                             const int* __restrict__ csr_src,
                                             const float* __restrict__ inv_deg) {
    int t = threadIdx.x;
    int wave = t >> 6, lane = t & 63;
    int g = lane >> 4, l16 = lane & 15;
    int x = blockIdx.x & 7;
    int G = blockIdx.x >> 3;
    int slice = x >> 1, sub = x & 1;
    int node = G * 8 + sub * 4 + wave;        // 1250*8 = 10000
    int s = row_ofs[node], e = row_ofs[node + 1];
    const uint2* base = (const uint2*)hcat + slice * 16 + l16;  // row = 128 uint2
    float a0 = 0.f, a1 = 0.f, a2 = 0.f, a3 = 0.f;
    int j = s + g;
    for (; j + 4 < e; j += 8) {
        int i0 = csr_src[j], i1 = csr_src[j + 4];
        uint2 v0 = base[(size_t)i0 * 128];
        uint2 v1 = base[(size_t)i1 * 128];
        a0 += bflo(v0.x) + bflo(v1.x);
        a1 += bfhi(v0.x) + bfhi(v1.x);
        a2 += bflo(v0.y) + bflo(v1.y);
        a3 += bfhi(v0.y) + bfhi(v1.y);
    }
    if (j < e) {
        uint2 v0 = base[(size_t)csr_src[j] * 128];
        a0 += bflo(v0.x); a1 += bfhi(v0.x); a2 += bflo(v0.y); a3 += bfhi(v0.y);
    }
    a0 += __shfl_xor(a0, 16); a0 += __shfl_xor(a0, 32);
    a1 += __shfl_xor(a1, 16); a1 += __shfl_xor(a1, 32);
    a2 += __shfl_xor(a2, 16); a2 += __shfl_xor(a2, 32);
    a3 += __shfl_xor(a3, 16); a3 += __shfl_xor(a3, 32);
    if (g == 0) {
        float inv = inv_deg[node];
        uint2 p;
        p.x = packbf(a0 * inv, a1 * inv);
        p.y = packbf(a2 * inv, a3 * inv);
        ((uint2*)hcat)[(size_t)node * 128 + 64 + slice * 16 + l16] = p;
    }
}

// ---------------- MFMA GEMM: Z(bf16) = hcat @ Wcat, + column stats ----------------
// grid = 157*2 = 314; block tile 64rows x 128cols; wave tile 32x64 (two 32x32x16 MFMAs)
// no LDS: B (256KB) is L2-resident; A streamed dwordx4.
__global__ __launch_bounds__(256) void k_gemm(const unsigned short* __restrict__ hcat,
                                              const unsigned short* __restrict__ wcatT,
                                              unsigned short* __restrict__ Z,
                                              float* __restrict__ stats) {
    int t = threadIdx.x;
    int wave = t >> 6, lane = t & 63;
    int m = lane & 31, half = lane >> 5;
    int mblk = blockIdx.x >> 1;               // 0..156
    int nhalf = blockIdx.x & 1;
    int row0 = mblk * 64 + (wave >> 1) * 32;
    int col0 = nhalf * 128 + (wave & 1) * 64;

    int ar = row0 + m; if (ar > NN - 1) ar = NN - 1;   // clamp; invalid rows masked at store
    const unsigned short* Ap  = hcat  + (size_t)ar * KK + half * 8;
    const unsigned short* Bp0 = wcatT + (size_t)(col0 + m) * KK + half * 8;
    const unsigned short* Bp1 = Bp0 + (size_t)32 * KK;

    f32x16 acc0, acc1;
#pragma unroll
    for (int i = 0; i < 16; ++i) { acc0[i] = 0.f; acc1[i] = 0.f; }

#pragma unroll 8
    for (int k0 = 0; k0 < KK; k0 += 16) {
        bf16x8 a  = *(const bf16x8*)(Ap  + k0);
        bf16x8 b0 = *(const bf16x8*)(Bp0 + k0);
        bf16x8 b1 = *(const bf16x8*)(Bp1 + k0);
        acc0 = __builtin_amdgcn_mfma_f32_32x32x16_bf16(a, b0, acc0, 0, 0, 0);
        acc1 = __builtin_amdgcn_mfma_f32_32x32x16_bf16(a, b1, acc1, 0, 0, 0);
    }

#pragma unroll
    for (int ct = 0; ct < 2; ++ct) {
        int cc = col0 + ct * 32 + m;
        float s = 0.f, s2 = 0.f;
#pragma unroll
        for (int reg = 0; reg < 16; ++reg) {
            int r = row0 + (reg & 3) + 8 * (reg >> 2) + 4 * half;
            if (r < NN) {
                float v = (ct == 0) ? acc0[reg] : acc1[reg];
                Z[(size_t)r * DIM + cc] = f2bf(v);
                s += v;
                s2 += v * v;
            }
        }
        s  += __shfl_down(s, 32);
        s2 += __shfl_down(s2, 32);
        if (half == 0) {
            atomicAdd(&stats[cc], s);
            atomicAdd(&stats[DIM + cc], s2);
        }
    }
}

// ---------------- BN normalize + activation ----------------
// grid = 1250; 8 rows/block; lane group of 32 covers 256 cols via uint4 (8 bf16)
__global__ __launch_bounds__(256) void k_norm(const unsigned short* __restrict__ Zb,
                                              const float* __restrict__ stats,
                                              const float* __restrict__ gam,
                                              const float* __restrict__ bet,
                                              unsigned short* __restrict__ hcat,
                                              float* __restrict__ out, int act) {
    int t = threadIdx.x;
    int c8 = (t & 31) * 8;
    int r = blockIdx.x * 8 + (t >> 5);
    float sc[8], sh[8];
#pragma unroll
    for (int i = 0; i < 8; ++i) {
        int c = c8 + i;
        float mu  = stats[c] * (1.0f / NN);
        float var = stats[DIM + c] * (1.0f / NN) - mu * mu;
        float k = rsqrtf(var + EPS_BN) * gam[c];
        sc[i] = k;
        sh[i] = bet[c] - mu * k;
    }
    uint4 v = *(const uint4*)(Zb + (size_t)r * DIM + c8);
    float f[8] = {bflo(v.x), bfhi(v.x), bflo(v.y), bfhi(v.y),
                  bflo(v.z), bfhi(v.z), bflo(v.w), bfhi(v.w)};
#pragma unroll
    for (int i = 0; i < 8; ++i) f[i] = f[i] * sc[i] + sh[i];
    if (act) {
        float4 o0, o1;
        o0.x = 1.0f / (1.0f + __expf(-f[0]));
        o0.y = 1.0f / (1.0f + __expf(-f[1]));
        o0.z = 1.0f / (1.0f + __expf(-f[2]));
        o0.w = 1.0f / (1.0f + __expf(-f[3]));
        o1.x = 1.0f / (1.0f + __expf(-f[4]));
        o1.y = 1.0f / (1.0f + __expf(-f[5]));
        o1.z = 1.0f / (1.0f + __expf(-f[6]));
        o1.w = 1.0f / (1.0f + __expf(-f[7]));
        *(float4*)(out + (size_t)r * DIM + c8)     = o0;
        *(float4*)(out + (size_t)r * DIM + c8 + 4) = o1;
    } else {
        uint4 p;
        p.x = packbf(fmaxf(f[0], 0.f), fmaxf(f[1], 0.f));
        p.y = packbf(fmaxf(f[2], 0.f), fmaxf(f[3], 0.f));
        p.z = packbf(fmaxf(f[4], 0.f), fmaxf(f[5], 0.f));
        p.w = packbf(fmaxf(f[6], 0.f), fmaxf(f[7], 0.f));
        *(uint4*)(hcat + (size_t)r * KK + c8) = p;
    }
}

extern "C" void kernel_launch(void* const* d_in, const int* in_sizes, int n_in,
                              void* d_out, int out_size, void* d_ws, size_t ws_size,
                              hipStream_t stream) {
    const float* x   = (const float*)d_in[0];
    const int*   src = (const int*)d_in[1];
    const int*   dst = (const int*)d_in[2];
    const float* Ws[3] = {(const float*)d_in[3], (const float*)d_in[8],  (const float*)d_in[13]};
    const float* Wn[3] = {(const float*)d_in[4], (const float*)d_in[9],  (const float*)d_in[14]};
    const float* gg[3] = {(const float*)d_in[6], (const float*)d_in[11], (const float*)d_in[16]};
    const float* be[3] = {(const float*)d_in[7], (const float*)d_in[12], (const float*)d_in[17]};
    float* out = (float*)d_out;

    // ---- workspace layout ----
    char* ws = (char*)d_ws;
    size_t off = 0;
    unsigned short* hcat = (unsigned short*)(ws + off); off += (size_t)NN * KK * 2;   // 10.24 MB
    unsigned short* zbuf = (unsigned short*)(ws + off); off += (size_t)NN * DIM * 2;  // 5.12 MB
    unsigned short* wcat = (unsigned short*)(ws + off); off += (size_t)3 * DIM * KK * 2;
    float* stats = (float*)(ws + off); off += 3 * 2 * DIM * sizeof(float);
    float* inv_deg = (float*)(ws + off); off += (size_t)NN * 4;
    int* deg_cnt = (int*)(ws + off); off += (size_t)NN * 4;
    int* row_ofs = (int*)(ws + off); off += (size_t)(NN + 1) * 4; off = (off + 255) & ~(size_t)255;
    int* cursor  = (int*)(ws + off); off += (size_t)NN * 4;
    int* csr_src = (int*)(ws + off); off += (size_t)EE * 4;
    (void)ws_size;

    // ---- prep: converts + zeroing (one dispatch) ----
    k_prep<<<2500 + 1536 + 48, 256, 0, stream>>>(x, hcat, Ws[0], Wn[0], Ws[1], Wn[1],
                                                 Ws[2], Wn[2], wcat, deg_cnt, stats);

    // ---- CSR build (layer-invariant) ----
    k_deg<<<(EE + 255) / 256, 256, 0, stream>>>(dst, deg_cnt, EE);
    k_scan<<<1, 256, 0, stream>>>(deg_cnt, row_ofs, cursor, inv_deg);
    k_fill<<<(EE + 255) / 256, 256, 0, stream>>>(src, dst, cursor, csr_src, EE);

    for (int L = 0; L < 3; ++L) {
        k_agg<<<NN, 256, 0, stream>>>(hcat, row_ofs, csr_src, inv_deg);
        k_gemm<<<157 * 2, 256, 0, stream>>>(hcat, wcat + (size_t)L * DIM * KK, zbuf,
                                            stats + L * 2 * DIM);
        k_norm<<<NN / 8, 256, 0, stream>>>(zbuf, stats + L * 2 * DIM, gg[L], be[L],
                                           hcat, out, (L == 2) ? 1 : 0);
    }
}